// Round 12
// baseline (545.145 us; speedup 1.0000x reference)
//
#include <hip/hip_runtime.h>

typedef unsigned short u16;
typedef unsigned int u32;
typedef __bf16 bf16x8 __attribute__((ext_vector_type(8)));
typedef float f32x4 __attribute__((ext_vector_type(4)));

#define N 4096
#define KD 128
#define NSTRIP 32
#define W 128            // strip width in cols (64 lanes x 2)
#define SROWS 4160       // C2T rows per strip (s = 0..4159)
#define SSTRIDE (SROWS * 64)   // u32 per strip = 266240
#define NBLK 130
#define TOTSTEP 4159     // N + 63
#define HUGEV 3.0e38f
#define TS 128
#define PADK 136

__device__ __forceinline__ u16 f2bf(float v) {
  u32 u = __float_as_uint(v);
  u += 0x7fffu + ((u >> 16) & 1u);   // RNE
  return (u16)(u >> 16);
}
__device__ __forceinline__ float bf2f(u16 b) { return __uint_as_float(((u32)b) << 16); }
__device__ __forceinline__ float bfround(float v) { return bf2f(f2bf(v)); }

__device__ __forceinline__ float dpp_shr1(float oldv, float src) {
  return __int_as_float(__builtin_amdgcn_update_dpp(
      __float_as_int(oldv), __float_as_int(src), 0x138, 0xF, 0xF, false));
}

// ---------------- norms + edge sentinels + C2T head/tail zero-fill ----------------
__global__ __launch_bounds__(256) void norms_kernel(const float* __restrict__ pred,
                                                    const float* __restrict__ tgt,
                                                    float* __restrict__ na, float* __restrict__ nb,
                                                    float* __restrict__ edgeG, u32* __restrict__ C2T) {
  const int t = blockIdx.x * 256 + threadIdx.x;
  if (t < NSTRIP * N) edgeG[t] = -1.0f;          // sentinel: DP values always >= 0
  if (t < NSTRIP * 8192) {                        // zero head rows s=0..63 and tail s=4095..4158
    const int strip = t >> 13, idx = t & 8191;
    const int s = (idx < 4096) ? (idx >> 6) : (4095 + ((idx - 4096) >> 6));
    C2T[(size_t)strip * SSTRIDE + s * 64 + (idx & 63)] = 0;
  }
  int gw = blockIdx.x * 4 + (threadIdx.x >> 6);
  int lane = threadIdx.x & 63;
  const float* base = (gw < N) ? (pred + (size_t)gw * KD) : (tgt + (size_t)(gw - N) * KD);
  float2 v = ((const float2*)base)[lane];
  float x = bfround(v.x), y = bfround(v.y);
  float s = x * x + y * y;
  #pragma unroll
  for (int off = 32; off > 0; off >>= 1) s += __shfl_xor(s, off);
  if (lane == 0) { if (gw < N) na[gw] = s; else nb[gw - N] = s; }
}

// ---------------- GEMM -> d2(bf16) -> diagonal-major C2T ----------------
__global__ __launch_bounds__(256) void gemm_kernel(const float* __restrict__ A, const float* __restrict__ B,
                                                   const float* __restrict__ na, const float* __restrict__ nb,
                                                   u32* __restrict__ C2T) {
  __shared__ u16 As[TS * PADK];
  __shared__ u16 Bs[TS * PADK];
  const int bi = blockIdx.y, bj = blockIdx.x;
  const int tid = threadIdx.x;
  {
    int row = tid >> 1, half = (tid & 1) * 64;
    const float* ga = A + (size_t)(bi * TS + row) * KD + half;
    const float* gb = B + (size_t)(bj * TS + row) * KD + half;
    u16* la = As + row * PADK + half;
    u16* lb = Bs + row * PADK + half;
    #pragma unroll
    for (int v = 0; v < 16; ++v) {
      float4 fa = ((const float4*)ga)[v];
      float4 fb = ((const float4*)gb)[v];
      *(ushort4*)(la + v * 4) = make_ushort4(f2bf(fa.x), f2bf(fa.y), f2bf(fa.z), f2bf(fa.w));
      *(ushort4*)(lb + v * 4) = make_ushort4(f2bf(fb.x), f2bf(fb.y), f2bf(fb.z), f2bf(fb.w));
    }
  }
  __syncthreads();
  const int wid = tid >> 6, lane = tid & 63;
  const int wr = (wid >> 1) * 64, wc = (wid & 1) * 64;
  const int l15 = lane & 15, l4 = lane >> 4;
  f32x4 acc[4][4] = {};
  #pragma unroll
  for (int ks = 0; ks < 4; ++ks) {
    bf16x8 af[4], bq[4];
    const int ko = ks * 32 + l4 * 8;
    #pragma unroll
    for (int m = 0; m < 4; ++m) af[m] = *(const bf16x8*)(As + (wr + m * 16 + l15) * PADK + ko);
    #pragma unroll
    for (int n = 0; n < 4; ++n) bq[n] = *(const bf16x8*)(Bs + (wc + n * 16 + l15) * PADK + ko);
    #pragma unroll
    for (int m = 0; m < 4; ++m)
      #pragma unroll
      for (int n = 0; n < 4; ++n)
        acc[m][n] = __builtin_amdgcn_mfma_f32_16x16x32_bf16(af[m], bq[n], acc[m][n], 0, 0, 0);
  }
  __syncthreads();   // done reading As/Bs; reuse As as the d2 tile T[128][136]
  #pragma unroll
  for (int m = 0; m < 4; ++m) {
    const int rl0 = wr + m * 16 + l4 * 4;
    #pragma unroll
    for (int n = 0; n < 4; ++n) {
      const int cl = wc + n * 16 + l15;
      const float nbv = nb[bj * TS + cl];
      #pragma unroll
      for (int e = 0; e < 4; ++e) {
        const int rl = rl0 + e;
        float d2v = fmaxf(na[bi * TS + rl] + nbv - 2.0f * acc[m][n][e], 0.0f);
        As[rl * PADK + cl] = f2bf(d2v);
      }
    }
  }
  __syncthreads();
  // transpose to diagonal-major: C2T[bj][bi*128 + sl][l] = pair(cols 2l,2l+1, row sl-l)
  const u32* Tp = (const u32*)As;                // u32 index = rl*68 + l (PADK/2 = 68)
  u32* outb = C2T + (size_t)bj * SSTRIDE + (size_t)(bi * TS) * 64 + lane;
  #pragma unroll 1
  for (int k = 0; k < 48; ++k) {
    const int sl = wid + 4 * k;
    if (sl < 191) {
      const int rl = sl - lane;
      if ((u32)rl < 128u) outb[sl * 64] = Tp[rl * 68 + lane];
    }
  }
}

// ---------------- wavefront DP, LDS-free steady state ----------------
#define STEP1(CU, IDX) { \
  const float ev = __int_as_float(__builtin_amdgcn_readlane(__float_as_int(vUse), (IDX))); \
  const float evv = lane0 ? ev : 0.0f; \
  const float Lc = dpp_shr1(evv, D1); \
  const float c0 = __uint_as_float((CU) << 16); \
  const float c1 = __uint_as_float((CU) & 0xFFFF0000u); \
  const float n0 = fmaxf(c0, fminf(fminf(D0, Lp), Lc)); \
  const float n1 = fmaxf(c1, fminf(fminf(D1, D0), n0)); \
  D0 = n0; D1 = n1; Lp = Lc; \
}

#define LDV(V) { \
  V##0 = pld[0];   V##1 = pld[64];  V##2 = pld[128]; V##3 = pld[192]; \
  V##4 = pld[256]; V##5 = pld[320]; V##6 = pld[384]; V##7 = pld[448]; \
  pld += 512; \
}

#define EST(p, v) __hip_atomic_store((p), (v), __ATOMIC_RELAXED, __HIP_MEMORY_SCOPE_AGENT)

#define CG(V, G0) { \
  float t0, t1, t2, t3, t4, t5, t6, t7; \
  STEP1(V##0, (G0) + 0); t0 = D1; \
  STEP1(V##1, (G0) + 1); t1 = D1; \
  STEP1(V##2, (G0) + 2); t2 = D1; \
  STEP1(V##3, (G0) + 3); t3 = D1; \
  STEP1(V##4, (G0) + 4); t4 = D1; \
  STEP1(V##5, (G0) + 5); t5 = D1; \
  STEP1(V##6, (G0) + 6); t6 = D1; \
  STEP1(V##7, (G0) + 7); t7 = D1; \
  if (e63q2) { \
    float* ea = eB + (q * 32 - 63 + (G0)); \
    EST(ea + 0, t0); EST(ea + 1, t1); EST(ea + 2, t2); EST(ea + 3, t3); \
    EST(ea + 4, t4); EST(ea + 5, t5); EST(ea + 6, t6); EST(ea + 7, t7); \
  } else if (e63 && q == 1 && (G0) == 24) { \
    EST(eB, t7); \
  } \
}

__global__ __launch_bounds__(64) void dp_kernel(const u32* __restrict__ C2T, float* __restrict__ edgeG,
                                                float* __restrict__ out) {
  const int bid = blockIdx.x;
  const int S = ((bid & 7) << 2) | (bid >> 3);        // 4 consecutive strips per XCD
  const int lane = threadIdx.x;
  const bool lane0 = (lane == 0);
  const u32* cb = C2T + (size_t)S * SSTRIDE + lane;
  float* eB = edgeG + (size_t)S * N;
  float* eI = edgeG + (size_t)(S - 1) * N;            // valid only when S>0
  const bool sp = (S > 0);
  const bool do_edge = (S != NSTRIP - 1);
  const bool e63 = do_edge && (lane == 63);
  const bool l32 = lane < 32;

  float D0 = HUGEV, D1 = HUGEV;
  float Lp = (S == 0 && lane == 0) ? -HUGEV : HUGEV;  // strip-0 corner seed
  float v0p = HUGEV;
  if (sp && l32)
    v0p = __hip_atomic_fetch_add(eI + lane, 0.0f, __ATOMIC_RELAXED, __HIP_MEMORY_SCOPE_AGENT);

  const u32* pld = cb;
  u32 A0, A1, A2, A3, A4, A5, A6, A7;
  u32 B0, B1, B2, B3, B4, B5, B6, B7;
  LDV(A)                                              // steps 0..7
  LDV(B)                                              // steps 8..15

  #pragma unroll 1
  for (int q = 0; q < 129; ++q) {
    // poll this block's edges (prefetched last block; sentinel = -1)
    if (sp && q <= 127) {
      int it = 0;
      while (__any(v0p < 0.0f)) {
        __builtin_amdgcn_s_sleep(1);
        if (l32)
          v0p = __hip_atomic_fetch_add(eI + q * 32 + lane, 0.0f,
                                       __ATOMIC_RELAXED, __HIP_MEMORY_SCOPE_AGENT);
        if (++it > (1 << 20)) break;
      }
    }
    const float vUse = v0p;
    if (sp && q + 1 <= 127 && l32)                    // prefetch next block's edges
      v0p = __hip_atomic_fetch_add(eI + (q + 1) * 32 + lane, 0.0f,
                                   __ATOMIC_RELAXED, __HIP_MEMORY_SCOPE_AGENT);
    const bool e63q2 = e63 && (q >= 2);

    CG(A, 0)  LDV(A)
    CG(B, 8)  LDV(B)
    CG(A, 16) LDV(A)
    CG(B, 24) LDV(B)
  }

  // epilogue block q=129: steps 4128..4158 (31 steps); capture answer at s=4158
  {
    const int q = 129;
    const float vUse = v0p;                           // stale; feeds only dead rows
    const bool e63q2 = e63;
    CG(A, 0)  LDV(A)                                  // loads s 4144..4151
    CG(B, 8)  LDV(B)                                  // loads s 4152..4159
    CG(A, 16)
    {
      float t0, t1, t2, t3, t4, t5, t6;
      STEP1(B0, 24); t0 = D1;
      STEP1(B1, 25); t1 = D1;
      STEP1(B2, 26); t2 = D1;
      STEP1(B3, 27); t3 = D1;
      STEP1(B4, 28); t4 = D1;
      STEP1(B5, 29); t5 = D1;
      STEP1(B6, 30); t6 = D1;                         // s=4158: row 4095 done
      if (e63q2) {
        float* ea = eB + (q * 32 - 63 + 24);
        EST(ea + 0, t0); EST(ea + 1, t1); EST(ea + 2, t2); EST(ea + 3, t3);
        EST(ea + 4, t4); EST(ea + 5, t5); EST(ea + 6, t6);
      }
      if (S == NSTRIP - 1 && lane == 63) out[0] = sqrtf(fmaxf(t6, 0.0f));
    }
  }
}

extern "C" void kernel_launch(void* const* d_in, const int* in_sizes, int n_in,
                              void* d_out, int out_size, void* d_ws, size_t ws_size,
                              hipStream_t stream) {
  const float* pred = (const float*)d_in[0];
  const float* tgt  = (const float*)d_in[1];
  char* ws = (char*)d_ws;
  u32* C2T  = (u32*)ws;                               // 32 strips x 4160 x 64 u32 = 34.1 MB
  float* na = (float*)(ws + (size_t)NSTRIP * SSTRIDE * 4);
  float* nb = na + N;
  float* edgeG = nb + N;                              // 32*N floats, sentinel-init'd
  float* out = (float*)d_out;

  hipLaunchKernelGGL(norms_kernel, dim3(2048), dim3(256), 0, stream, pred, tgt, na, nb, edgeG, C2T);
  hipLaunchKernelGGL(gemm_kernel, dim3(32, 32), dim3(256), 0, stream, pred, tgt, na, nb, C2T);
  hipLaunchKernelGGL(dp_kernel, dim3(NSTRIP), dim3(64), 0, stream, C2T, edgeG, out);
}